// Round 9
// baseline (300.553 us; speedup 1.0000x reference)
//
#include <hip/hip_runtime.h>

#define S_LEN    2048
#define D_MODEL  1024
#define N_HEADS  16
#define HEAD_DIM 64
#define BATCH    2

typedef __bf16 bf16x8 __attribute__((ext_vector_type(8)));
typedef float  floatx4 __attribute__((ext_vector_type(4)));
typedef float  floatx16 __attribute__((ext_vector_type(16)));

__device__ __forceinline__ unsigned short f2bf(float f) {
    union { float f; unsigned int u; } v;
    v.f = f;
    unsigned int u = v.u;
    u += 0x7fffu + ((u >> 16) & 1u);   // RNE
    return (unsigned short)(u >> 16);
}

// pack two floats to bf16 pair, RNE (3 inst)
__device__ __forceinline__ unsigned int pk_rne(float a, float b) {
    union { float f; unsigned int u; } ua, ub;
    ua.f = a; ub.f = b;
    unsigned int x = ua.u + 0x7fffu + ((ua.u >> 16) & 1u);
    unsigned int y = ub.u + 0x7fffu + ((ub.u >> 16) & 1u);
    return __builtin_amdgcn_perm(y, x, 0x07060302);  // low = a, high = b
}

// pack two floats to bf16 pair, TRUNCATION (1 inst). Used for P only: the bias
// cancels because l is summed from the same truncated values (MFMA ones*P).
__device__ __forceinline__ unsigned int pk_tr(float a, float b) {
    union { float f; unsigned int u; } ua, ub;
    ua.f = a; ub.f = b;
    return __builtin_amdgcn_perm(ub.u, ua.u, 0x07060302);
}

__device__ __forceinline__ void gload_lds16(const unsigned short* g, unsigned short* l) {
    __builtin_amdgcn_global_load_lds(
        (const __attribute__((address_space(1))) void*)(const void*)g,
        (__attribute__((address_space(3))) void*)(void*)l,
        16, 0, 0);
}

#define LDS_FENCE() __asm__ volatile("s_waitcnt lgkmcnt(0)" ::: "memory")

// ---------- fused prep: fp32->bf16 for q,k,v  +  W[K][N] -> Wt[N][K] bf16 ----------
struct PrepArgs {
    const float* src[3]; unsigned short* dst[3];
    const float* W[4];   unsigned short* Wt[4];
};

#define CONV_BLOCKS (3 * 4096)

__global__ void prep_kernel(PrepArgs args) {
    const int bid = blockIdx.x;
    if (bid < CONV_BLOCKS) {
        const int t   = bid >> 12;
        const int blk = bid & 4095;
        const int i   = blk * 256 + threadIdx.x;
        float4 f = reinterpret_cast<const float4*>(args.src[t])[i];
        ushort4 o;
        o.x = f2bf(f.x); o.y = f2bf(f.y); o.z = f2bf(f.z); o.w = f2bf(f.w);
        reinterpret_cast<ushort4*>(args.dst[t])[i] = o;
    } else {
        __shared__ unsigned short tile[64][65];
        const int r  = bid - CONV_BLOCKS;
        const int w  = r >> 8;
        const int xy = r & 255;
        const int n0 = (xy & 15) * 64, k0 = (xy >> 4) * 64;
        const float* W = args.W[w];
        unsigned short* Wt = args.Wt[w];
        for (int rep = 0; rep < 16; ++rep) {
            int e = rep * 256 + threadIdx.x;
            int kk = e >> 6, nn = e & 63;
            tile[kk][nn] = f2bf(W[(size_t)(k0 + kk) * D_MODEL + n0 + nn]);
        }
        __syncthreads();
        for (int rep = 0; rep < 16; ++rep) {
            int e = rep * 256 + threadIdx.x;
            int nn = e >> 6, kk = e & 63;
            Wt[(size_t)(n0 + nn) * D_MODEL + k0 + kk] = tile[kk][nn];
        }
    }
}

// ---------- QKV GEMM (unchanged structure; passed R6/R7) ----------
template <int TM, int TN, int MODE>
__device__ __forceinline__
void gemm_body(const unsigned short* __restrict__ A,
               const unsigned short* __restrict__ Bt,
               const float* __restrict__ bias,
               void* __restrict__ out,
               int m0, int n0, float scale,
               unsigned short* smem) {
    constexpr int MT = TM / 32;
    constexpr int NT = TN / 32;
    unsigned short* As = smem;
    unsigned short* Bs = smem + TM * 32;
    const int tid  = threadIdx.x;
    const int wid  = tid >> 6;
    const int lane = tid & 63;

    floatx4 acc[MT][NT];
#pragma unroll
    for (int i = 0; i < MT; ++i)
#pragma unroll
        for (int j = 0; j < NT; ++j) acc[i][j] = (floatx4)0.0f;

    const int srow = lane >> 2;
    const int gch  = (lane & 3) ^ ((srow >> 1) & 3);
    const int wr = (wid >> 1) * (TM / 2);
    const int wc = (wid & 1) * (TN / 2);
    const int fr = lane & 15;
    const int fq = lane >> 4;
    const int swz = (fq ^ ((fr >> 1) & 3)) * 8;

    for (int k0 = 0; k0 < D_MODEL; k0 += 32) {
        if (k0) __syncthreads();
#pragma unroll
        for (int ci = 0; ci < (TM + TN) / 64; ++ci) {
            const int c = wid + ci * 4;
            if (c < TM / 16) {
                const int row = c * 16 + srow;
                gload_lds16(A + (size_t)(m0 + row) * D_MODEL + k0 + gch * 8, As + c * 512);
            } else {
                const int cb = c - TM / 16;
                const int row = cb * 16 + srow;
                gload_lds16(Bt + (size_t)(n0 + row) * D_MODEL + k0 + gch * 8, Bs + cb * 512);
            }
        }
        __syncthreads();

        bf16x8 af[MT], bfv[NT];
#pragma unroll
        for (int t = 0; t < MT; ++t)
            af[t] = *reinterpret_cast<const bf16x8*>(As + (wr + t * 16 + fr) * 32 + swz);
#pragma unroll
        for (int t = 0; t < NT; ++t)
            bfv[t] = *reinterpret_cast<const bf16x8*>(Bs + (wc + t * 16 + fr) * 32 + swz);
#pragma unroll
        for (int mt = 0; mt < MT; ++mt)
#pragma unroll
            for (int nt = 0; nt < NT; ++nt) {
                if (MODE == 1)
                    acc[mt][nt] = __builtin_amdgcn_mfma_f32_16x16x32_bf16(af[mt], bfv[nt], acc[mt][nt], 0, 0, 0);
                else
                    acc[mt][nt] = __builtin_amdgcn_mfma_f32_16x16x32_bf16(bfv[nt], af[mt], acc[mt][nt], 0, 0, 0);
            }
    }

    __syncthreads();  // staging LDS reused for store repack

    if (MODE == 0) {
        unsigned short* rp = smem + wid * 1024;
        unsigned short* outbf = (unsigned short*)out;
        float4 b4[NT];
#pragma unroll
        for (int nt = 0; nt < NT; ++nt)
            b4[nt] = *reinterpret_cast<const float4*>(bias + n0 + wc + nt * 16 + fq * 4);
        const int hh = (n0 + wc) >> 6;
#pragma unroll
        for (int mt = 0; mt < MT; ++mt) {
#pragma unroll
            for (int nt = 0; nt < NT; ++nt) {
                const float* bb = reinterpret_cast<const float*>(&b4[nt]);
#pragma unroll
                for (int p = 0; p < 2; ++p) {
                    float v0 = (acc[mt][nt][2 * p]     + bb[2 * p])     * scale;
                    float v1 = (acc[mt][nt][2 * p + 1] + bb[2 * p + 1]) * scale;
                    *reinterpret_cast<unsigned int*>(rp + fr * 64 + nt * 16 + fq * 4 + 2 * p) = pk_rne(v0, v1);
                }
            }
            LDS_FENCE();
#pragma unroll
            for (int j = 0; j < 2; ++j) {
                const int row = (lane >> 3) + j * 8;
                const int m = m0 + wr + mt * 16 + row;
                const int b = m >> 11, s = m & (S_LEN - 1);
                uint4 val = *reinterpret_cast<const uint4*>(rp + row * 64 + (lane & 7) * 8);
                *reinterpret_cast<uint4*>(outbf + (((size_t)(b * N_HEADS + hh) * S_LEN + s) * HEAD_DIM) + (lane & 7) * 8) = val;
            }
            LDS_FENCE();
        }
    } else {
        unsigned short* rp = smem + wid * 1024;
        unsigned short* outbf = (unsigned short*)out;
        float bval[NT];
#pragma unroll
        for (int nt = 0; nt < NT; ++nt) bval[nt] = bias[n0 + wc + nt * 16 + fr];
#pragma unroll
        for (int nt = 0; nt < NT; ++nt) {
#pragma unroll
            for (int mt = 0; mt < MT; ++mt) {
#pragma unroll
                for (int p = 0; p < 2; ++p) {
                    float v0 = acc[mt][nt][2 * p]     + bval[nt];
                    float v1 = acc[mt][nt][2 * p + 1] + bval[nt];
                    *reinterpret_cast<unsigned int*>(rp + fr * 64 + mt * 16 + fq * 4 + 2 * p) = pk_rne(v0, v1);
                }
            }
            LDS_FENCE();
#pragma unroll
            for (int j = 0; j < 2; ++j) {
                const int row = (lane >> 3) + j * 8;
                const int n = n0 + wc + nt * 16 + row;
                const int h = n >> 6, dk = n & 63;
                const int mch = m0 + wr + (lane & 7) * 8;
                const int b = mch >> 11, s = mch & (S_LEN - 1);
                uint4 val = *reinterpret_cast<const uint4*>(rp + row * 64 + (lane & 7) * 8);
                *reinterpret_cast<uint4*>(outbf + ((size_t)(b * N_HEADS + h) * HEAD_DIM + dk) * S_LEN + s) = val;
            }
            LDS_FENCE();
        }
    }
}

struct QKVArgs {
    const unsigned short* A[3];
    const unsigned short* Bt[3];
    const float* bias[3];
    unsigned short* out[3];
};

__global__ __launch_bounds__(256)
void qkv_gemm_kernel(QKVArgs args) {
    __shared__ __align__(16) unsigned short smem[8192];
    const int z = blockIdx.z;
    const int m0 = blockIdx.y * 128;
    const int n0 = blockIdx.x * 128;
    if (z == 0)
        gemm_body<128, 128, 0>(args.A[0], args.Bt[0], args.bias[0], args.out[0], m0, n0, 0.18033688011112f, smem);
    else if (z == 1)
        gemm_body<128, 128, 0>(args.A[1], args.Bt[1], args.bias[1], args.out[1], m0, n0, 1.0f, smem);
    else
        gemm_body<128, 128, 1>(args.A[2], args.Bt[2], args.bias[2], args.out[2], m0, n0, 1.0f, smem);
}

// ---------- O projection with fused kv-split reduction ----------
// A[m][k] = (O0[m][k] + O1[m][k]) * 1/(l0[m,h]+l1[m,h]), h = k>>6, converted to
// bf16 during staging (VGPR roundtrip, A-regs prefetched one k-tile ahead).
// As/Bs double-buffered -> single barrier per iter. C = A * Wot^T + bo, fp32 out.
__global__ __launch_bounds__(256)
void oproj_gemm_kernel(const float* __restrict__ Opart,   // [2][M][1024] fp32
                       const float* __restrict__ lbuf,    // [2][M][16]  fp32
                       const unsigned short* __restrict__ Wot,
                       const float* __restrict__ bias,
                       float* __restrict__ out) {
    __shared__ __align__(16) unsigned short smem[12288];  // As[2]:4K Bs[2]:16K = 24KB

    const int tid  = threadIdx.x;
    const int wid  = tid >> 6;
    const int lane = tid & 63;
    const int m0 = blockIdx.y * 64;
    const int n0 = blockIdx.x * 128;

    // A staging (all 256 threads): row = tid&63, k-chunk fq = tid>>6 (8 elems)
    const int arow = tid & 63;
    const int afq  = tid >> 6;
    const int am   = m0 + arow;
    const float* a0p = Opart + (size_t)am * D_MODEL + afq * 8;              // split 0
    const float* a1p = Opart + 4194304 + (size_t)am * D_MODEL + afq * 8;    // split 1
    const int aoff = arow * 32 + ((afq ^ ((arow >> 1) & 3)) * 8);           // swizzled LDS dest

    // B staging (gload_lds, 2 chunks/wave)
    const int srow = lane >> 2;
    const int gch  = (lane & 3) ^ ((srow >> 1) & 3);

    // fragment indices
    const int wr = (wid >> 1) * 32;
    const int wc = (wid & 1) * 64;
    const int fr = lane & 15;
    const int fq = lane >> 4;
    const int swz = (fq ^ ((fr >> 1) & 3)) * 8;

    floatx4 acc[2][4];
#pragma unroll
    for (int i = 0; i < 2; ++i)
#pragma unroll
        for (int j = 0; j < 4; ++j) acc[i][j] = (floatx4)0.0f;

    // ---- prologue: tile 0 ----
    float4 ra0 = *reinterpret_cast<const float4*>(a0p);
    float4 ra1 = *reinterpret_cast<const float4*>(a0p + 4);
    float4 rb0 = *reinterpret_cast<const float4*>(a1p);
    float4 rb1 = *reinterpret_cast<const float4*>(a1p + 4);
    float  rlv = lbuf[(size_t)am * 16] + lbuf[65536 + (size_t)am * 16];
#pragma unroll
    for (int ci = 0; ci < 2; ++ci) {
        const int cb = wid + ci * 4;
        const int row = cb * 16 + srow;
        gload_lds16(Wot + (size_t)(n0 + row) * D_MODEL + gch * 8, smem + 4096 + cb * 512);
    }
    {
        const float linv = __builtin_amdgcn_rcpf(rlv);
        uint4 u;
        u.x = pk_rne((ra0.x + rb0.x) * linv, (ra0.y + rb0.y) * linv);
        u.y = pk_rne((ra0.z + rb0.z) * linv, (ra0.w + rb0.w) * linv);
        u.z = pk_rne((ra1.x + rb1.x) * linv, (ra1.y + rb1.y) * linv);
        u.w = pk_rne((ra1.z + rb1.z) * linv, (ra1.w + rb1.w) * linv);
        *reinterpret_cast<uint4*>(smem + aoff) = u;
    }
    __syncthreads();

    for (int k0 = 0; k0 < D_MODEL; k0 += 32) {
        const int buf = (k0 >> 5) & 1;
        unsigned short* Asb = smem + buf * 2048;
        unsigned short* Bsb = smem + 4096 + buf * 4096;
        unsigned short* Asn = smem + (buf ^ 1) * 2048;
        unsigned short* Bsn = smem + 4096 + (buf ^ 1) * 4096;
        const bool more = (k0 + 32) < D_MODEL;
        if (more) {
            const int k1 = k0 + 32;
            ra0 = *reinterpret_cast<const float4*>(a0p + k1);
            ra1 = *reinterpret_cast<const float4*>(a0p + k1 + 4);
            rb0 = *reinterpret_cast<const float4*>(a1p + k1);
            rb1 = *reinterpret_cast<const float4*>(a1p + k1 + 4);
            rlv = lbuf[(size_t)am * 16 + (k1 >> 6)] + lbuf[65536 + (size_t)am * 16 + (k1 >> 6)];
#pragma unroll
            for (int ci = 0; ci < 2; ++ci) {
                const int cb = wid + ci * 4;
                const int row = cb * 16 + srow;
                gload_lds16(Wot + (size_t)(n0 + row) * D_MODEL + k1 + gch * 8, Bsn + cb * 512);
            }
        }

        bf16x8 af[2], bfv[4];
#pragma unroll
        for (int t = 0; t < 2; ++t)
            af[t] = *reinterpret_cast<const bf16x8*>(Asb + (wr + t * 16 + fr) * 32 + swz);
#pragma unroll
        for (int t = 0; t < 4; ++t)
            bfv[t] = *reinterpret_cast<const bf16x8*>(Bsb + (wc + t * 16 + fr) * 32 + swz);
#pragma unroll
        for (int mt = 0; mt < 2; ++mt)
#pragma unroll
            for (int nt = 0; nt < 4; ++nt)
                acc[mt][nt] = __builtin_amdgcn_mfma_f32_16x16x32_bf16(bfv[nt], af[mt], acc[mt][nt], 0, 0, 0);

        if (more) {
            const float linv = __builtin_amdgcn_rcpf(rlv);
            uint4 u;
            u.x = pk_rne((ra0.x + rb0.x) * linv, (ra0.y + rb0.y) * linv);
            u.y = pk_rne((ra0.z + rb0.z) * linv, (ra0.w + rb0.w) * linv);
            u.z = pk_rne((ra1.x + rb1.x) * linv, (ra1.y + rb1.y) * linv);
            u.w = pk_rne((ra1.z + rb1.z) * linv, (ra1.w + rb1.w) * linv);
            *reinterpret_cast<uint4*>(Asn + aoff) = u;
        }
        __syncthreads();
    }

    // epilogue (MODE 2 style): acc rows = n-local, cols = m-local; fp32 [M][1024]
    float* rpf = reinterpret_cast<float*>(smem) + wid * 1024;  // 4 waves x 4KB <= 24KB
    float4 b4[4];
#pragma unroll
    for (int nt = 0; nt < 4; ++nt)
        b4[nt] = *reinterpret_cast<const float4*>(bias + n0 + wc + nt * 16 + fq * 4);
#pragma unroll
    for (int mt = 0; mt < 2; ++mt) {
#pragma unroll
        for (int nt = 0; nt < 4; ++nt) {
            const float* bb = reinterpret_cast<const float*>(&b4[nt]);
#pragma unroll
            for (int p = 0; p < 2; ++p) {
                float2 w;
                w.x = acc[mt][nt][2 * p]     + bb[2 * p];
                w.y = acc[mt][nt][2 * p + 1] + bb[2 * p + 1];
                *reinterpret_cast<float2*>(rpf + fr * 64 + nt * 16 + fq * 4 + 2 * p) = w;
            }
        }
        LDS_FENCE();
#pragma unroll
        for (int j = 0; j < 4; ++j) {
            const int row = (lane >> 4) + j * 4;
            const int m = m0 + wr + mt * 16 + row;
            float4 val = *reinterpret_cast<const float4*>(rpf + row * 64 + (lane & 15) * 4);
            *reinterpret_cast<float4*>(out + (size_t)m * D_MODEL + n0 + wc + (lane & 15) * 4) = val;
        }
        LDS_FENCE();
    }
}

// ---------- attention: 32x32 MFMA, register P-transform, kv-split x2 ----------
// grid (16, NH, BATCH*2): z = b*2 + split; each block covers 128 q x 1024 kv,
// writing unnormalized fp32 O-partial + l-partial. 1024 blocks x 4 waves
// -> 16 waves/CU. l is summed from the PACKED (truncated) P via MFMA(ones,P)
// so P truncation bias cancels in O/l. Pack = 1 v_perm per pair.
__global__ __launch_bounds__(256, 4)
void attn_kernel(const unsigned short* __restrict__ qhp,
                 const unsigned short* __restrict__ khp,
                 const unsigned short* __restrict__ vtp,
                 float* __restrict__ opart,     // [2][B*S][1024]
                 float* __restrict__ lbuf) {    // [2][B*S][16]
    __shared__ __align__(16) unsigned short Ks[128 * 64];   // [kv][dk] swizzled
    __shared__ __align__(16) unsigned short Vs[64 * 128];   // [d][kv]  swizzled

    const int tid  = threadIdx.x;
    const int wid  = tid >> 6;
    const int lane = tid & 63;
    const int z = blockIdx.z;
    const int b = z >> 1, split = z & 1;
    const int h = blockIdx.y;
    const int q0 = blockIdx.x * 128;
    const int q31  = lane & 31;
    const int half = lane >> 5;

    const unsigned short* qbase = qhp + (size_t)(b * N_HEADS + h) * S_LEN * HEAD_DIM;
    const unsigned short* kbase = khp + (size_t)(b * N_HEADS + h) * S_LEN * HEAD_DIM;
    const unsigned short* vbase = vtp + (size_t)(b * N_HEADS + h) * HEAD_DIM * S_LEN;

    bf16x8 qf[4];
#pragma unroll
    for (int kc = 0; kc < 4; ++kc)
        qf[kc] = *reinterpret_cast<const bf16x8*>(
            qbase + (size_t)(q0 + wid * 32 + q31) * HEAD_DIM + kc * 16 + half * 8);

    bf16x8 ones;
#pragma unroll
    for (int i = 0; i < 8; ++i) ones[i] = (__bf16)1.0f;

    floatx16 o_acc[2];
    o_acc[0] = (floatx16)0.0f; o_acc[1] = (floatx16)0.0f;
    floatx16 l_acc = (floatx16)0.0f;

    const int srow  = lane >> 3;
    const int gch   = (lane & 7) ^ srow;
    const int srow4 = lane >> 4;

    for (int ii = 0; ii < 8; ++ii) {
        const int kv0 = (split * 8 + ii) * 128;
        __syncthreads();
#pragma unroll
        for (int i = 0; i < 4; ++i) {
            const int c = wid * 4 + i;
            const int krow = c * 8 + srow;
            gload_lds16(kbase + (size_t)(kv0 + krow) * HEAD_DIM + gch * 8, Ks + c * 512);
            const int vrow = c * 4 + srow4;
            const int gchv = (lane & 15) ^ (vrow & 7);
            gload_lds16(vbase + (size_t)vrow * S_LEN + kv0 + gchv * 8, Vs + c * 512);
        }
        __syncthreads();

#pragma unroll
        for (int mt = 0; mt < 4; ++mt) {
            const int krow = mt * 32 + q31;
            const int ksw  = krow & 7;
            floatx16 st = (floatx16)0.0f;
#pragma unroll
            for (int kc = 0; kc < 4; ++kc) {
                bf16x8 kf = *reinterpret_cast<const bf16x8*>(
                    Ks + krow * 64 + (((kc * 2 + half) ^ ksw) * 8));
                st = __builtin_amdgcn_mfma_f32_32x32x16_bf16(kf, qf[kc], st, 0, 0, 0);
            }

            float p[16];
#pragma unroll
            for (int r = 0; r < 16; ++r) p[r] = __builtin_amdgcn_exp2f(st[r]);

            unsigned int u[8], x[8];
#pragma unroll
            for (int g = 0; g < 8; ++g) u[g] = pk_tr(p[2 * g], p[2 * g + 1]);
#pragma unroll
            for (int g = 0; g < 8; ++g) x[g] = (unsigned int)__shfl_xor((int)u[g], 32);

#pragma unroll
            for (int c = 0; c < 2; ++c) {
                uint4 pd;
                pd.x = half ? x[4 * c + 2] : u[4 * c];
                pd.y = half ? x[4 * c + 3] : u[4 * c + 1];
                pd.z = half ? u[4 * c + 2] : x[4 * c];
                pd.w = half ? u[4 * c + 3] : x[4 * c + 1];
                union { uint4 i; bf16x8 v; } pf; pf.i = pd;
                const int cg = mt * 2 + c;
                l_acc = __builtin_amdgcn_mfma_f32_32x32x16_bf16(ones, pf.v, l_acc, 0, 0, 0);
#pragma unroll
                for (int dm = 0; dm < 2; ++dm) {
                    const int drow = dm * 32 + q31;
                    bf16x8 vf = *reinterpret_cast<const bf16x8*>(
                        Vs + drow * 128 + (((cg * 2 + half) ^ (drow & 7)) * 8));
                    o_acc[dm] = __builtin_amdgcn_mfma_f32_32x32x16_bf16(vf, pf.v, o_acc[dm], 0, 0, 0);
                }
            }
        }
    }

    // epilogue: unnormalized O-partial (fp32) + l-partial
    const int q = q0 + wid * 32 + q31;
    const size_t m = (size_t)b * S_LEN + q;
    float* obase = opart + (size_t)split * 4194304 + m * D_MODEL + h * HEAD_DIM;
#pragma unroll
    for (int dm = 0; dm < 2; ++dm)
#pragma unroll
        for (int g = 0; g < 8; ++g) {
            const int d = dm * 32 + 8 * (g >> 1) + 2 * (g & 1) + 4 * half;
            float2 w;
            w.x = o_acc[dm][2 * g];
            w.y = o_acc[dm][2 * g + 1];
            *reinterpret_cast<float2*>(obase + d) = w;
        }
    if (!half) lbuf[(size_t)split * 65536 + m * 16 + h] = l_acc[0];
}

extern "C" void kernel_launch(void* const* d_in, const int* in_sizes, int n_in,
                              void* d_out, int out_size, void* d_ws, size_t ws_size,
                              hipStream_t stream) {
    (void)in_sizes; (void)n_in; (void)out_size; (void)ws_size;
    const float* q  = (const float*)d_in[0];
    const float* k  = (const float*)d_in[1];
    const float* v  = (const float*)d_in[2];
    // d_in[3] = mask: mathematical no-op in the reference
    const float* Wq = (const float*)d_in[4];
    const float* bq = (const float*)d_in[5];
    const float* Wk = (const float*)d_in[6];
    const float* bk = (const float*)d_in[7];
    const float* Wv = (const float*)d_in[8];
    const float* bv = (const float*)d_in[9];
    const float* Wo = (const float*)d_in[10];
    const float* bo = (const float*)d_in[11];
    float* out = (float*)d_out;

    char* ws = (char*)d_ws;
    const size_t MB = 1024 * 1024;
    // layout (peak 58.5 MB):
    //  [0,32MB):  qb(8) kb(8) vb(8) Wqt(2) Wkt(2) Wvt(2) pad(2)  -- dead after qkv
    //             -> overlaid by Opart [2][4M] fp32 (32MB) written by attn
    //  [32,34):   Wot (live through oproj)
    //  [34,58):   qhb khb vtb (8MB each)
    //  [58,58.5): lbuf [2][65536] fp32
    unsigned short* qb   = (unsigned short*)(ws);
    unsigned short* kb   = (unsigned short*)(ws + 8 * MB);
    unsigned short* vb   = (unsigned short*)(ws + 16 * MB);
    unsigned short* Wqt  = (unsigned short*)(ws + 24 * MB);
    unsigned short* Wkt  = (unsigned short*)(ws + 26 * MB);
    unsigned short* Wvt  = (unsigned short*)(ws + 28 * MB);
    unsigned short* Wot  = (unsigned short*)(ws + 32 * MB);
    unsigned short* qhb  = (unsigned short*)(ws + 34 * MB);
    unsigned short* khb  = (unsigned short*)(ws + 42 * MB);
    unsigned short* vtb  = (unsigned short*)(ws + 50 * MB);
    float*          opart = (float*)(ws);
    float*          lbuf  = (float*)(ws + 58 * MB);

    PrepArgs pargs;
    pargs.src[0] = q;  pargs.src[1] = k;  pargs.src[2] = v;
    pargs.dst[0] = qb; pargs.dst[1] = kb; pargs.dst[2] = vb;
    pargs.W[0] = Wq;  pargs.W[1] = Wk;  pargs.W[2] = Wv;  pargs.W[3] = Wo;
    pargs.Wt[0] = Wqt; pargs.Wt[1] = Wkt; pargs.Wt[2] = Wvt; pargs.Wt[3] = Wot;
    prep_kernel<<<dim3(CONV_BLOCKS + 1024), 256, 0, stream>>>(pargs);

    QKVArgs gargs;
    gargs.A[0] = qb;  gargs.A[1] = kb;  gargs.A[2] = vb;
    gargs.Bt[0] = Wqt; gargs.Bt[1] = Wkt; gargs.Bt[2] = Wvt;
    gargs.bias[0] = bq; gargs.bias[1] = bk; gargs.bias[2] = bv;
    gargs.out[0] = qhb; gargs.out[1] = khb; gargs.out[2] = vtb;
    qkv_gemm_kernel<<<dim3(8, 32, 3), 256, 0, stream>>>(gargs);

    attn_kernel<<<dim3(S_LEN / 128, N_HEADS, BATCH * 2), 256, 0, stream>>>(qhb, khb, vtb, opart, lbuf);

    oproj_gemm_kernel<<<dim3(8, 64), 256, 0, stream>>>(opart, lbuf, Wot, bo, out);
}